// Round 3
// baseline (230.597 us; speedup 1.0000x reference)
//
#include <hip/hip_runtime.h>

#pragma clang fp contract(off)

#define NB 8
#define NN 25200
#define NCLS 80
#define NSTR 85
#define MAXDET 300
#define CONF_T 0.4f
#define IOU_T 0.45f
#define MAX_WH_C 4096.0f

#define NBIN 1024
#define BINSHIFT 14
#define BINBASE 0x3EC00000u   // bits(0.375) < bits of any valid score (>0.4)
#define SELN 512
#define BPI 99                // blocks per image in select: 99*256 >= 25200
#define SORTN 2048            // fallback kernel only

// ---------------- helpers ----------------
__device__ __forceinline__ float cand_score(const float* __restrict__ p) {
    float obj = p[4];
    float best = p[5] * obj;
    for (int j = 1; j < NCLS; ++j) {
        float s = p[5 + j] * obj;
        if (s > best) best = s;
    }
    return ((obj > CONF_T) && (best > CONF_T)) ? best : -1.0f;
}
__device__ __forceinline__ int cand_cls(const float* __restrict__ p) {
    float obj = p[4];
    float best = p[5] * obj; int bc = 0;
    for (int j = 1; j < NCLS; ++j) {
        float s = p[5 + j] * obj;
        if (s > best) { best = s; bc = j; }
    }
    return bc;
}
__device__ __forceinline__ bool iou_gt(float ax1, float ay1, float ax2, float ay2, float aarea,
                                       float bx1, float by1, float bx2, float by2, float barea) {
    float lx = fmaxf(ax1, bx1);
    float ly = fmaxf(ay1, by1);
    float rx = fminf(ax2, bx2);
    float ry = fminf(ay2, by2);
    float iw = fmaxf(rx - lx, 0.0f);
    float ih = fmaxf(ry - ly, 0.0f);
    float inter = iw * ih;
    float iou = inter / ((aarea + barea - inter) + 1e-9f);
    return iou > IOU_T;
}

// =============== Kernel 1: score/cls + global histogram (LDS-staged, coalesced) ===============
#define PREP_ROWS 64
__global__ __launch_bounds__(256) void prep_kernel(const float* __restrict__ pred,
                                                   float* __restrict__ score_ws,
                                                   int* __restrict__ cls_ws,
                                                   int* __restrict__ hist) {
    __shared__ float st[PREP_ROWS * NSTR];   // 21760 B
    const int R0 = blockIdx.x * PREP_ROWS;
    const float* src = pred + (size_t)R0 * NSTR;
    const int tid = threadIdx.x;
    for (int i = tid; i < PREP_ROWS * NSTR; i += 256) st[i] = src[i];
    __syncthreads();

    int row = tid >> 2, part = tid & 3;
    const float* pr = st + row * NSTR;
    float obj = pr[4];
    float best = -1.0f; int bc = part * 20;
    const float* pc = pr + 5 + part * 20;
#pragma unroll
    for (int k = 0; k < 20; ++k) {
        float s = pc[k] * obj;
        if (s > best) { best = s; bc = part * 20 + k; }   // strict >: first-index argmax
    }
    // combine 4 parts (adjacent lanes), tie -> lower class index
#pragma unroll
    for (int d = 1; d <= 2; d <<= 1) {
        float ob = __shfl_xor(best, d);
        int   oc = __shfl_xor(bc, d);
        if (ob > best || (ob == best && oc < bc)) { best = ob; bc = oc; }
    }
    if (part == 0) {
        int grow = R0 + row;
        bool valid = (obj > CONF_T) && (best > CONF_T);
        score_ws[grow] = valid ? best : -1.0f;
        cls_ws[grow] = bc;
        if (valid) {
            int ib = grow / NN;
            int bin = (int)((__float_as_uint(best) - BINBASE) >> BINSHIFT);
            atomicAdd(&hist[ib * NBIN + bin], 1);
        }
    }
}

// =============== Kernel 2: threshold + compact selected list ===============
__global__ __launch_bounds__(256) void select_kernel(const float* __restrict__ pred,
                                                     const float* __restrict__ score_ws,
                                                     const int* __restrict__ cls_ws,
                                                     const int* __restrict__ hist,
                                                     int* __restrict__ cnt_ws,
                                                     unsigned long long* __restrict__ sel_key,
                                                     float* __restrict__ sel_x1, float* __restrict__ sel_y1,
                                                     float* __restrict__ sel_x2, float* __restrict__ sel_y2,
                                                     float* __restrict__ sel_area, float* __restrict__ sel_score,
                                                     float* __restrict__ sel_cls, int* __restrict__ sel_idx) {
    __shared__ int sT;
    const int ib = blockIdx.x / BPI;
    const int tid = threadIdx.x;
    if (tid < 64) {
        int lane = tid;
        int acc = 0; int S[16];
#pragma unroll
        for (int k = 15; k >= 0; --k) { acc += hist[ib * NBIN + lane * 16 + k]; S[k] = acc; }
        int tot = acc;
        int incl = tot;
#pragma unroll
        for (int d = 1; d < 64; d <<= 1) {
            int v = __shfl_down(incl, d);
            if (lane + d < 64) incl += v;
        }
        int E = incl - tot;   // sum over lanes > lane
        int Tl = NBIN;
#pragma unroll
        for (int k = 0; k < 16; ++k)
            if (Tl == NBIN && S[k] + E <= SELN) Tl = lane * 16 + k;
#pragma unroll
        for (int d = 1; d < 64; d <<= 1) {
            int o = __shfl_xor(Tl, d);
            if (o < Tl) Tl = o;
        }
        if (tid == 0) sT = Tl;
    }
    __syncthreads();
    int T = sT;
    int g = (blockIdx.x % BPI) * 256 + tid;
    if (g < NN) {
        float s = score_ws[(size_t)ib * NN + g];
        if (s > 0.0f) {
            int bin = (int)((__float_as_uint(s) - BINBASE) >> BINSHIFT);
            if (bin >= T) {
                int pos = atomicAdd(&cnt_ws[ib], 1);
                if (pos < SELN) {
                    int o = ib * SELN + pos;
                    const float* p = pred + ((size_t)ib * NN + g) * NSTR;
                    float cx = p[0], cy = p[1], w = p[2], h = p[3];
                    int c = cls_ws[(size_t)ib * NN + g];
                    float off = (float)c * MAX_WH_C;
                    float x1 = (cx - w * 0.5f) + off;
                    float y1 = (cy - h * 0.5f) + off;
                    float x2 = (cx + w * 0.5f) + off;
                    float y2 = (cy + h * 0.5f) + off;
                    sel_key[o] = ((unsigned long long)__float_as_uint(s) << 32)
                                 | (unsigned int)(0xFFFFFFFFu - (unsigned int)g);
                    sel_x1[o] = x1; sel_y1[o] = y1; sel_x2[o] = x2; sel_y2[o] = y2;
                    sel_area[o] = (x2 - x1) * (y2 - y1);
                    sel_score[o] = s; sel_cls[o] = (float)c; sel_idx[o] = g;
                }
            }
        }
    }
}

// =============== in-register bitonic sort (512 elems, 8/lane, ascending on inverted keys) ===============
template<int KK, int J>
__device__ __forceinline__ void bsort_stage(unsigned long long (&k_)[8], int (&p_)[8], int lane) {
    if constexpr (J >= 8) {
        constexpr int LX = J >> 3;
        bool lower = ((lane & LX) == 0);
#pragma unroll
        for (int r = 0; r < 8; ++r) {
            unsigned long long ok = __shfl_xor(k_[r], LX);
            int op = __shfl_xor(p_[r], LX);
            int e = lane * 8 + r;
            bool dir_up = ((e & KK) == 0);
            bool want_min = (lower == dir_up);
            bool take = want_min ? (ok < k_[r]) : (ok > k_[r]);
            if (take) { k_[r] = ok; p_[r] = op; }
        }
    } else {
#pragma unroll
        for (int r = 0; r < 8; ++r) {
            if ((r & J) == 0) {
                int r2 = r | J;
                int e = lane * 8 + r;
                bool dir_up = ((e & KK) == 0);
                bool swp = dir_up ? (k_[r] > k_[r2]) : (k_[r] < k_[r2]);
                if (swp) {
                    unsigned long long tk = k_[r]; k_[r] = k_[r2]; k_[r2] = tk;
                    int tp = p_[r]; p_[r] = p_[r2]; p_[r2] = tp;
                }
            }
        }
    }
}
template<int KK, int J>
__device__ __forceinline__ void bsort_j(unsigned long long (&k_)[8], int (&p_)[8], int lane) {
    bsort_stage<KK, J>(k_, p_, lane);
    if constexpr (J > 1) bsort_j<KK, (J >> 1)>(k_, p_, lane);
}
template<int KK>
__device__ __forceinline__ void bsort_k(unsigned long long (&k_)[8], int (&p_)[8], int lane) {
    bsort_j<KK, (KK >> 1)>(k_, p_, lane);
    if constexpr (KK < SELN) bsort_k<(KK << 1)>(k_, p_, lane);
}

// =============== Kernel 3: sort + mask + greedy resolve + outputs (one block/image) ===============
__global__ __launch_bounds__(1024) void resolve_kernel(
        const float* __restrict__ pred, const float* __restrict__ logits,
        const float* __restrict__ score_ws, const int* __restrict__ cls_ws,
        const int* __restrict__ hist, const int* __restrict__ cnt_ws,
        const unsigned long long* __restrict__ sel_key,
        const float* __restrict__ sel_x1, const float* __restrict__ sel_y1,
        const float* __restrict__ sel_x2, const float* __restrict__ sel_y2,
        const float* __restrict__ sel_area, const float* __restrict__ sel_score,
        const float* __restrict__ sel_cls, const int* __restrict__ sel_idx,
        float* __restrict__ out) {
    __shared__ unsigned long long s_mask[SELN][8];     // 32 KB (rank space)
    __shared__ unsigned long long s_invkey[SELN];      // 4 KB
    __shared__ int s_rankslot[SELN];
    __shared__ float s_ox1[SELN], s_oy1[SELN], s_ox2[SELN], s_oy2[SELN];
    __shared__ float s_oarea[SELN], s_oscore[SELN], s_ocls[SELN];
    __shared__ int s_oidx[SELN];
    __shared__ float kx1[MAXDET], ky1[MAXDET], kx2[MAXDET], ky2[MAXDET], karea[MAXDET];
    __shared__ float kscore[MAXDET], kcls[MAXDET];
    __shared__ int kidx[MAXDET];
    __shared__ int s_kc;

    const int b = blockIdx.x;
    const int tid = threadIdx.x;
    const int lane = tid & 63;
    const int wid = tid >> 6;
    const float* predb = pred + (size_t)b * NN * NSTR;
    const float* logb  = logits + (size_t)b * NN * NCLS;

    int cnt = cnt_ws[b]; if (cnt > SELN) cnt = SELN;

    // ---- Phase 1 (wave 0): total + in-register sort ----
    if (wid == 0) {
        unsigned long long k_[8]; int p_[8];
#pragma unroll
        for (int r = 0; r < 8; ++r) {
            int e = lane * 8 + r;
            unsigned long long key = (e < cnt) ? sel_key[b * SELN + e] : 0ull;
            k_[r] = ~key;      // ascending on inverted = descending on key; pads sort last
            p_[r] = e;
        }
        bsort_k<2>(k_, p_, lane);
#pragma unroll
        for (int r = 0; r < 8; ++r) {
            int e = lane * 8 + r;
            s_rankslot[e] = p_[r];
            s_invkey[e] = k_[r];
        }
    }
    __syncthreads();

    // ---- Phase 2: gather rank-ordered attributes ----
    for (int e = tid; e < cnt; e += 1024) {
        int slot = b * SELN + s_rankslot[e];
        s_ox1[e] = sel_x1[slot]; s_oy1[e] = sel_y1[slot];
        s_ox2[e] = sel_x2[slot]; s_oy2[e] = sel_y2[slot];
        s_oarea[e] = sel_area[slot]; s_oscore[e] = sel_score[slot];
        s_ocls[e] = sel_cls[slot]; s_oidx[e] = sel_idx[slot];
    }
    __syncthreads();

    // ---- Phase 3: full suppression mask in rank space ----
    {
        int i = tid >> 1;
        if (i < cnt) {
            float ax1 = s_ox1[i], ay1 = s_oy1[i], ax2 = s_ox2[i], ay2 = s_oy2[i], aar = s_oarea[i];
            for (int wi = 0; wi < 4; ++wi) {
                int w = ((tid & 1) << 2) + wi;
                unsigned long long m = 0ull;
                int jbase = w << 6;
                for (int bit = 0; bit < 64; ++bit) {
                    int j = jbase + bit;
                    if (j >= cnt) break;
                    bool s;
                    if (j == i) s = true;   // diagonal: pop clears own bit
                    else s = iou_gt(ax1, ay1, ax2, ay2, aar,
                                    s_ox1[j], s_oy1[j], s_ox2[j], s_oy2[j], s_oarea[j]);
                    m |= (unsigned long long)s << bit;
                }
                s_mask[i][w] = m;
            }
        }
    }
    __syncthreads();

    // ---- Phase 4 (wave 0): greedy resolve + (rare) exact continuation ----
    if (wid == 0) {
        int total = 0;
#pragma unroll
        for (int k = 0; k < 16; ++k) total += hist[b * NBIN + lane * 16 + k];
#pragma unroll
        for (int d = 32; d >= 1; d >>= 1) total += __shfl_xor(total, d);

        unsigned long long rem = 0ull;
        if (lane < 8) {
            int lo = lane << 6;
            if (cnt >= lo + 64) rem = ~0ull;
            else if (cnt > lo) rem = (1ull << (cnt - lo)) - 1ull;
        }
        int kc = 0;
        while (kc < MAXDET) {
            unsigned long long bal = __ballot((int)(rem != 0ull));
            if (bal == 0ull) break;
            int w0 = __builtin_ctzll(bal);
            unsigned long long word = __shfl(rem, w0);
            int e = (w0 << 6) + __builtin_ctzll(word);
            if (lane == 0) {
                kx1[kc] = s_ox1[e]; ky1[kc] = s_oy1[e]; kx2[kc] = s_ox2[e]; ky2[kc] = s_oy2[e];
                karea[kc] = s_oarea[e]; kscore[kc] = s_oscore[e];
                kcls[kc] = s_ocls[e]; kidx[kc] = s_oidx[e];
            }
            kc++;
            unsigned long long mrow = (lane < 8) ? s_mask[e][lane] : 0ull;
            rem &= ~mrow;
        }

        // continuation: only if <300 kept and candidates below threshold remain (never on this data)
        if (kc < MAXDET && total > cnt) {
            unsigned long long prevkey = (cnt > 0) ? ~s_invkey[cnt - 1] : ~0ull;
            const float* sb = score_ws + (size_t)b * NN;
            while (kc < MAXDET) {
                unsigned long long best = 0ull;
                for (int i0 = lane; i0 < NN; i0 += 64) {
                    float s = sb[i0];
                    if (s > 0.0f) {
                        unsigned long long key = ((unsigned long long)__float_as_uint(s) << 32)
                                                 | (unsigned int)(0xFFFFFFFFu - (unsigned int)i0);
                        if (key < prevkey && key > best) best = key;
                    }
                }
#pragma unroll
                for (int d = 32; d >= 1; d >>= 1) {
                    unsigned long long o = __shfl_xor(best, d);
                    if (o > best) best = o;
                }
                if (best == 0ull) break;
                prevkey = best;
                int gi = (int)(0xFFFFFFFFu - (unsigned int)(best & 0xFFFFFFFFull));
                float sc = __uint_as_float((unsigned int)(best >> 32));
                const float* pp = predb + (size_t)gi * NSTR;
                float cx = pp[0], cy = pp[1], w = pp[2], h = pp[3];
                int c = cls_ws[(size_t)b * NN + gi];
                float off = (float)c * MAX_WH_C;
                float x1 = (cx - w * 0.5f) + off;
                float y1 = (cy - h * 0.5f) + off;
                float x2 = (cx + w * 0.5f) + off;
                float y2 = (cy + h * 0.5f) + off;
                float ar = (x2 - x1) * (y2 - y1);
                bool f = false;
                for (int t = lane; t < kc; t += 64)
                    if (iou_gt(kx1[t], ky1[t], kx2[t], ky2[t], karea[t], x1, y1, x2, y2, ar)) f = true;
                if (!__any((int)f)) {
                    if (lane == 0) {
                        kx1[kc] = x1; ky1[kc] = y1; kx2[kc] = x2; ky2[kc] = y2;
                        karea[kc] = ar; kscore[kc] = sc; kcls[kc] = (float)c; kidx[kc] = gi;
                    }
                    kc++;
                }
            }
        }
        if (lane == 0) s_kc = kc;
    }
    __syncthreads();

    // ---- Phase 5: outputs (every element written every launch) ----
    int kc = s_kc;
    if (tid < MAXDET) {
        int t = tid;
        float o0 = 0, o1 = 0, o2 = 0, o3 = 0, o4 = 0, o5 = 0;
        if (t < kc) {
            int idx = kidx[t];
            const float* pp = predb + (size_t)idx * NSTR;
            float cx = pp[0], cy = pp[1], w = pp[2], h = pp[3];
            o0 = cx - w * 0.5f; o1 = cy - h * 0.5f;
            o2 = cx + w * 0.5f; o3 = cy + h * 0.5f;
            o4 = kscore[t];     o5 = kcls[t];
        }
        float* dd = out + (size_t)b * (MAXDET * 6) + (size_t)t * 6;
        dd[0] = o0; dd[1] = o1; dd[2] = o2; dd[3] = o3; dd[4] = o4; dd[5] = o5;
        out[(size_t)NB * MAXDET * 6 + (size_t)NB * MAXDET * NCLS + (size_t)b * MAXDET + t] =
            (t < kc) ? 1.0f : 0.0f;
    }
    float* lbase = out + (size_t)NB * MAXDET * 6 + (size_t)b * (MAXDET * NCLS);
    for (int t = wid; t < MAXDET; t += 16) {
        float* dst = lbase + (size_t)t * NCLS;
        if (t < kc) {
            const float* src = logb + (size_t)kidx[t] * NCLS;
            for (int c = lane; c < NCLS; c += 64) dst[c] = src[c];
        } else {
            for (int c = lane; c < NCLS; c += 64) dst[c] = 0.0f;
        }
    }
}

// =============== Fallback: self-contained round-2 kernel (used only if ws too small) ===============
__global__ __launch_bounds__(1024) void fallback_kernel(const float* __restrict__ pred,
                                                        const float* __restrict__ logits,
                                                        float* __restrict__ out) {
    __shared__ unsigned long long s_keys[SORTN];
    __shared__ float sel_x1[SORTN], sel_y1[SORTN], sel_x2[SORTN], sel_y2[SORTN];
    __shared__ float sel_area[SORTN], sel_cls[SORTN];
    __shared__ int   sel_idx[SORTN];
    __shared__ float kx1[MAXDET], ky1[MAXDET], kx2[MAXDET], ky2[MAXDET], karea[MAXDET];
    __shared__ float kscore[MAXDET], kcls[MAXDET];
    __shared__ int   kidx[MAXDET];
    __shared__ int   s_hist[NBIN];
    __shared__ int   s_suppk[64];
    __shared__ unsigned int s_supmask[64][2];
    __shared__ int   s_kc, s_T, s_cnt;

    const int b = blockIdx.x;
    const int tid = threadIdx.x;
    const int lane = tid & 63;
    const int wid = tid >> 6;
    const float* predb = pred + (size_t)b * NN * NSTR;
    const float* logb  = logits + (size_t)b * NN * NCLS;

    int kc_total = 0;
    int prevT = NBIN;

    while (kc_total < MAXDET && prevT > 0) {
        s_hist[tid] = 0;
        if (tid == 0) { s_cnt = 0; s_T = NBIN; }
        __syncthreads();
        for (int i = tid; i < NN; i += 1024) {
            float s = cand_score(predb + (size_t)i * NSTR);
            if (s > 0.0f) {
                int bin = (int)((__float_as_uint(s) - BINBASE) >> BINSHIFT);
                if (bin < prevT) atomicAdd(&s_hist[bin], 1);
            }
        }
        __syncthreads();
        for (int d = 1; d < NBIN; d <<= 1) {
            int v = s_hist[tid] + ((tid + d < NBIN) ? s_hist[tid + d] : 0);
            __syncthreads();
            s_hist[tid] = v;
            __syncthreads();
        }
        if (s_hist[tid] <= SORTN) atomicMin(&s_T, tid);
        __syncthreads();
        int T = s_T;
        int rem_total = s_hist[0];
        if (T >= prevT) {
            if (rem_total == 0) { prevT = 0; break; }
            T = prevT - 1;
        }
        __syncthreads();
        for (int i = tid; i < NN; i += 1024) {
            float s = cand_score(predb + (size_t)i * NSTR);
            if (s > 0.0f) {
                int bin = (int)((__float_as_uint(s) - BINBASE) >> BINSHIFT);
                if (bin >= T && bin < prevT) {
                    int pos = atomicAdd(&s_cnt, 1);
                    if (pos < SORTN)
                        s_keys[pos] = ((unsigned long long)__float_as_uint(s) << 32)
                                      | (unsigned int)(0xFFFFFFFFu - (unsigned int)i);
                }
            }
        }
        __syncthreads();
        int cnt = s_cnt; if (cnt > SORTN) cnt = SORTN;
        int npow = 64; while (npow < cnt) npow <<= 1;
        for (int i = cnt + tid; i < npow; i += 1024) s_keys[i] = 0ull;
        __syncthreads();
        for (int k = 2; k <= npow; k <<= 1) {
            for (int j = k >> 1; j > 0; j >>= 1) {
                for (int idx = tid; idx < npow; idx += 1024) {
                    int p = idx ^ j;
                    if (p > idx) {
                        unsigned long long a = s_keys[idx], c = s_keys[p];
                        bool desc = ((idx & k) == 0);
                        if (desc ? (a < c) : (a > c)) { s_keys[idx] = c; s_keys[p] = a; }
                    }
                }
                __syncthreads();
            }
        }
        for (int t = tid; t < cnt; t += 1024) {
            unsigned long long key = s_keys[t];
            int i = (int)(0xFFFFFFFFu - (unsigned int)(key & 0xFFFFFFFFull));
            const float* p = predb + (size_t)i * NSTR;
            float cx = p[0], cy = p[1], w = p[2], h = p[3];
            int c = cand_cls(p);
            float off = (float)c * MAX_WH_C;
            float x1 = (cx - w * 0.5f) + off;
            float y1 = (cy - h * 0.5f) + off;
            float x2 = (cx + w * 0.5f) + off;
            float y2 = (cy + h * 0.5f) + off;
            sel_x1[t] = x1; sel_y1[t] = y1; sel_x2[t] = x2; sel_y2[t] = y2;
            sel_area[t] = (x2 - x1) * (y2 - y1);
            sel_cls[t] = (float)c;
            sel_idx[t] = i;
        }
        __syncthreads();
        int nb2 = (cnt + 63) >> 6;
        for (int batch = 0; batch < nb2; ++batch) {
            int kcb = kc_total;
            if (kcb >= MAXDET) break;
            if (tid < 64) { s_suppk[tid] = 0; s_supmask[tid][0] = 0u; s_supmask[tid][1] = 0u; }
            __syncthreads();

            int cloc = tid >> 4, ch = tid & 15;
            int gi = batch * 64 + cloc;
            bool validc = gi < cnt;
            float ax1 = 0, ay1 = 0, ax2 = 0, ay2 = 0, aar = 0;
            if (validc) {
                ax1 = sel_x1[gi]; ay1 = sel_y1[gi];
                ax2 = sel_x2[gi]; ay2 = sel_y2[gi]; aar = sel_area[gi];
            }
            bool flag = false;
            if (validc) {
                for (int t = ch; t < kcb; t += 16) {
                    if (iou_gt(kx1[t], ky1[t], kx2[t], ky2[t], karea[t],
                               ax1, ay1, ax2, ay2, aar)) flag = true;
                }
            }
            unsigned long long bal = __ballot((int)flag);
            if ((lane & 15) == 0) {
                unsigned int sub = (unsigned int)((bal >> (lane & 48)) & 0xFFFFull);
                s_suppk[cloc] = (sub != 0u);
            }
            unsigned int mbits = 0;
            if (validc) {
                for (int jj = 0; jj < 4; ++jj) {
                    int j = (ch << 2) + jj;
                    int gj = batch * 64 + j;
                    if (j > cloc && gj < cnt) {
                        if (iou_gt(ax1, ay1, ax2, ay2, aar,
                                   sel_x1[gj], sel_y1[gj], sel_x2[gj], sel_y2[gj], sel_area[gj]))
                            mbits |= 1u << (j & 31);
                    }
                }
            }
            if (mbits) atomicOr(&s_supmask[cloc][(ch >> 3) & 1], mbits);
            __syncthreads();

            if (wid == 0) {
                unsigned long long mask =
                    ((unsigned long long)s_supmask[lane][1] << 32) | s_supmask[lane][0];
                bool validj = (batch * 64 + lane) < cnt;
                unsigned long long rem = __ballot((int)(validj && (s_suppk[lane] == 0)));
                unsigned long long keepbits = 0;
                int kcount = kcb;
                while (rem && kcount < MAXDET) {
                    int i = __builtin_ctzll(rem);
                    rem &= rem - 1;
                    keepbits |= 1ull << i;
                    ++kcount;
                    unsigned long long mi = __shfl(mask, i);
                    rem &= ~mi;
                }
                if ((keepbits >> lane) & 1ull) {
                    int pos = kcb + __popcll(keepbits & ((1ull << lane) - 1ull));
                    int g2 = batch * 64 + lane;
                    kx1[pos] = sel_x1[g2]; ky1[pos] = sel_y1[g2];
                    kx2[pos] = sel_x2[g2]; ky2[pos] = sel_y2[g2];
                    karea[pos] = sel_area[g2];
                    kcls[pos] = sel_cls[g2]; kidx[pos] = sel_idx[g2];
                    kscore[pos] = __uint_as_float((unsigned int)(s_keys[g2] >> 32));
                }
                if (lane == 0) s_kc = kcount;
            }
            __syncthreads();
            kc_total = s_kc;
            __syncthreads();
        }
        prevT = T;
    }

    __syncthreads();
    int kc = kc_total;
    if (tid < MAXDET) {
        int t = tid;
        float o0 = 0, o1 = 0, o2 = 0, o3 = 0, o4 = 0, o5 = 0;
        if (t < kc) {
            int idx = kidx[t];
            const float* pp = predb + (size_t)idx * NSTR;
            float cx = pp[0], cy = pp[1], w = pp[2], h = pp[3];
            o0 = cx - w * 0.5f; o1 = cy - h * 0.5f;
            o2 = cx + w * 0.5f; o3 = cy + h * 0.5f;
            o4 = kscore[t];     o5 = kcls[t];
        }
        float* dd = out + (size_t)b * (MAXDET * 6) + (size_t)t * 6;
        dd[0] = o0; dd[1] = o1; dd[2] = o2; dd[3] = o3; dd[4] = o4; dd[5] = o5;
        out[(size_t)NB * MAXDET * 6 + (size_t)NB * MAXDET * NCLS + (size_t)b * MAXDET + t] =
            (t < kc) ? 1.0f : 0.0f;
    }
    float* lbase = out + (size_t)NB * MAXDET * 6 + (size_t)b * (MAXDET * NCLS);
    for (int t = wid; t < MAXDET; t += 16) {
        float* dst = lbase + (size_t)t * NCLS;
        if (t < kc) {
            const float* src = logb + (size_t)kidx[t] * NCLS;
            for (int c = lane; c < NCLS; c += 64) dst[c] = src[c];
        } else {
            for (int c = lane; c < NCLS; c += 64) dst[c] = 0.0f;
        }
    }
}

extern "C" void kernel_launch(void* const* d_in, const int* in_sizes, int n_in,
                              void* d_out, int out_size, void* d_ws, size_t ws_size,
                              hipStream_t stream) {
    const float* pred   = (const float*)d_in[0];
    const float* logits = (const float*)d_in[1];
    float* out = (float*)d_out;

    // ws layout
    const size_t off_hist  = 0;                         // 8*1024*4 = 32768
    const size_t off_cnt   = 32768;                     // 8*4
    const size_t off_key   = 32800;                     // 8*512*8 = 32768
    const size_t off_x1    = 65568;                     // each float arr 8*512*4 = 16384
    const size_t off_y1    = off_x1 + 16384;
    const size_t off_x2    = off_y1 + 16384;
    const size_t off_y2    = off_x2 + 16384;
    const size_t off_area  = off_y2 + 16384;
    const size_t off_scr   = off_area + 16384;
    const size_t off_clsf  = off_scr + 16384;
    const size_t off_idx   = off_clsf + 16384;
    const size_t off_sws   = off_idx + 16384;           // 196640
    const size_t off_cws   = off_sws + (size_t)NB * NN * 4;
    const size_t need      = off_cws + (size_t)NB * NN * 4;   // 1,809,440 B

    if (d_ws == nullptr || ws_size < need) {
        fallback_kernel<<<NB, 1024, 0, stream>>>(pred, logits, out);
        return;
    }

    char* ws = (char*)d_ws;
    int* hist = (int*)(ws + off_hist);
    int* cnt_ws = (int*)(ws + off_cnt);
    unsigned long long* sel_key = (unsigned long long*)(ws + off_key);
    float* sel_x1 = (float*)(ws + off_x1);
    float* sel_y1 = (float*)(ws + off_y1);
    float* sel_x2 = (float*)(ws + off_x2);
    float* sel_y2 = (float*)(ws + off_y2);
    float* sel_area = (float*)(ws + off_area);
    float* sel_score = (float*)(ws + off_scr);
    float* sel_cls = (float*)(ws + off_clsf);
    int* sel_idx = (int*)(ws + off_idx);
    float* score_ws = (float*)(ws + off_sws);
    int* cls_ws = (int*)(ws + off_cws);

    hipMemsetAsync(ws, 0, off_key, stream);   // zero hist + counters

    prep_kernel<<<(NB * NN) / PREP_ROWS, 256, 0, stream>>>(pred, score_ws, cls_ws, hist);
    select_kernel<<<NB * BPI, 256, 0, stream>>>(pred, score_ws, cls_ws, hist, cnt_ws,
                                                sel_key, sel_x1, sel_y1, sel_x2, sel_y2,
                                                sel_area, sel_score, sel_cls, sel_idx);
    resolve_kernel<<<NB, 1024, 0, stream>>>(pred, logits, score_ws, cls_ws, hist, cnt_ws,
                                            sel_key, sel_x1, sel_y1, sel_x2, sel_y2,
                                            sel_area, sel_score, sel_cls, sel_idx, out);
}

// Round 4
// 118.489 us; speedup vs baseline: 1.9461x; 1.9461x over previous
//
#include <hip/hip_runtime.h>

#pragma clang fp contract(off)

#define NB 8
#define NN 25200
#define NCLS 80
#define NSTR 85
#define MAXDET 300
#define CONF_T 0.4f
#define IOU_T 0.45f
#define MAX_WH_C 4096.0f

#define NBIN 1024
#define BINSHIFT 14
#define BINBASE 0x3EC00000u   // bits(0.375) < bits of any valid score (>0.4)
#define SELN 512
#define BPI 99                // select blocks per image: 99*256 >= 25200
#define SORTN 2048            // fallback kernel only

typedef unsigned long long ull;

// ---------------- helpers ----------------
__device__ __forceinline__ float cand_score(const float* __restrict__ p) {
    float obj = p[4];
    float best = p[5] * obj;
    for (int j = 1; j < NCLS; ++j) {
        float s = p[5 + j] * obj;
        if (s > best) best = s;
    }
    return ((obj > CONF_T) && (best > CONF_T)) ? best : -1.0f;
}
__device__ __forceinline__ int cand_cls(const float* __restrict__ p) {
    float obj = p[4];
    float best = p[5] * obj; int bc = 0;
    for (int j = 1; j < NCLS; ++j) {
        float s = p[5 + j] * obj;
        if (s > best) { best = s; bc = j; }   // strict >: first-index argmax
    }
    return bc;
}
__device__ __forceinline__ bool iou_gt(float ax1, float ay1, float ax2, float ay2, float aarea,
                                       float bx1, float by1, float bx2, float by2, float barea) {
    float lx = fmaxf(ax1, bx1);
    float ly = fmaxf(ay1, by1);
    float rx = fminf(ax2, bx2);
    float ry = fminf(ay2, by2);
    float iw = fmaxf(rx - lx, 0.0f);
    float ih = fmaxf(ry - ly, 0.0f);
    float inter = iw * ih;
    float iou = inter / ((aarea + barea - inter) + 1e-9f);
    return iou > IOU_T;
}

// =============== Kernel 1: score + global histogram (float4 LDS staging) ===============
#define PREP_ROWS 64
__global__ __launch_bounds__(256) void prep_kernel(const float* __restrict__ pred,
                                                   float* __restrict__ score_ws,
                                                   int* __restrict__ hist) {
    __shared__ float st[PREP_ROWS * NSTR];   // 21760 B = 1360 float4
    const int R0 = blockIdx.x * PREP_ROWS;
    const float4* src = reinterpret_cast<const float4*>(pred + (size_t)R0 * NSTR);
    float4* dst4 = reinterpret_cast<float4*>(st);
    const int tid = threadIdx.x;
    for (int i = tid; i < PREP_ROWS * NSTR / 4; i += 256) dst4[i] = src[i];
    __syncthreads();

    int row = tid >> 2, part = tid & 3;
    const float* pr = st + row * NSTR;
    float obj = pr[4];
    float best = -1.0f; int bc = part * 20;
    const float* pc = pr + 5 + part * 20;
#pragma unroll
    for (int k = 0; k < 20; ++k) {
        float s = pc[k] * obj;
        if (s > best) { best = s; bc = part * 20 + k; }
    }
#pragma unroll
    for (int d = 1; d <= 2; d <<= 1) {
        float ob = __shfl_xor(best, d);
        int   oc = __shfl_xor(bc, d);
        if (ob > best || (ob == best && oc < bc)) { best = ob; bc = oc; }
    }
    if (part == 0) {
        int grow = R0 + row;
        bool valid = (obj > CONF_T) && (best > CONF_T);
        score_ws[grow] = valid ? best : -1.0f;
        if (valid) {
            int ib = grow / NN;
            int bin = (int)((__float_as_uint(best) - BINBASE) >> BINSHIFT);
            atomicAdd(&hist[ib * NBIN + bin], 1);
        }
    }
}

// =============== Kernel 2: threshold + compact selected list (cls recomputed) ===============
__global__ __launch_bounds__(256) void select_kernel(const float* __restrict__ pred,
                                                     const float* __restrict__ score_ws,
                                                     const int* __restrict__ hist,
                                                     int* __restrict__ cnt_ws,
                                                     ull* __restrict__ sel_key,
                                                     float* __restrict__ sel_x1, float* __restrict__ sel_y1,
                                                     float* __restrict__ sel_x2, float* __restrict__ sel_y2,
                                                     float* __restrict__ sel_area, float* __restrict__ sel_score,
                                                     float* __restrict__ sel_cls, int* __restrict__ sel_idx) {
    __shared__ int sT;
    const int ib = blockIdx.x / BPI;
    const int tid = threadIdx.x;
    if (tid < 64) {
        int lane = tid;
        int acc = 0; int S[16];
#pragma unroll
        for (int k = 15; k >= 0; --k) { acc += hist[ib * NBIN + lane * 16 + k]; S[k] = acc; }
        int tot = acc;
        int incl = tot;
#pragma unroll
        for (int d = 1; d < 64; d <<= 1) {
            int v = __shfl_down(incl, d);
            if (lane + d < 64) incl += v;
        }
        int E = incl - tot;   // sum over lanes > lane
        int Tl = NBIN;
#pragma unroll
        for (int k = 0; k < 16; ++k)
            if (Tl == NBIN && S[k] + E <= SELN) Tl = lane * 16 + k;
#pragma unroll
        for (int d = 1; d < 64; d <<= 1) {
            int o = __shfl_xor(Tl, d);
            if (o < Tl) Tl = o;
        }
        if (tid == 0) sT = Tl;
    }
    __syncthreads();
    int T = sT;
    int g = (blockIdx.x % BPI) * 256 + tid;
    if (g < NN) {
        float s = score_ws[(size_t)ib * NN + g];
        if (s > 0.0f) {
            int bin = (int)((__float_as_uint(s) - BINBASE) >> BINSHIFT);
            if (bin >= T) {
                int pos = atomicAdd(&cnt_ws[ib], 1);
                if (pos < SELN) {
                    int o = ib * SELN + pos;
                    const float* p = pred + ((size_t)ib * NN + g) * NSTR;
                    float cx = p[0], cy = p[1], w = p[2], h = p[3];
                    int c = cand_cls(p);
                    float off = (float)c * MAX_WH_C;
                    float x1 = (cx - w * 0.5f) + off;
                    float y1 = (cy - h * 0.5f) + off;
                    float x2 = (cx + w * 0.5f) + off;
                    float y2 = (cy + h * 0.5f) + off;
                    sel_key[o] = ((ull)__float_as_uint(s) << 32)
                                 | (unsigned int)(0xFFFFFFFFu - (unsigned int)g);
                    sel_x1[o] = x1; sel_y1[o] = y1; sel_x2[o] = x2; sel_y2[o] = y2;
                    sel_area[o] = (x2 - x1) * (y2 - y1);
                    sel_score[o] = s; sel_cls[o] = (float)c; sel_idx[o] = g;
                }
            }
        }
    }
}

// =============== Kernel 3: rank by counting + scatter to rank-ordered arrays ===============
__global__ __launch_bounds__(512) void rank_kernel(const int* __restrict__ cnt_ws,
                                                   const ull* __restrict__ sel_key,
                                                   const float* __restrict__ sel_x1, const float* __restrict__ sel_y1,
                                                   const float* __restrict__ sel_x2, const float* __restrict__ sel_y2,
                                                   const float* __restrict__ sel_area, const float* __restrict__ sel_score,
                                                   const float* __restrict__ sel_cls, const int* __restrict__ sel_idx,
                                                   float* __restrict__ ord_x1, float* __restrict__ ord_y1,
                                                   float* __restrict__ ord_x2, float* __restrict__ ord_y2,
                                                   float* __restrict__ ord_area, float* __restrict__ ord_score,
                                                   float* __restrict__ ord_cls, int* __restrict__ ord_idx) {
    __shared__ ull s_key[SELN];
    const int b = blockIdx.x;
    const int tid = threadIdx.x;
    int cnt = cnt_ws[b]; if (cnt > SELN) cnt = SELN;
    s_key[tid] = (tid < cnt) ? sel_key[b * SELN + tid] : 0ull;
    __syncthreads();
    ull k = s_key[tid];
    int r = 0;
    for (int j = 0; j < SELN; ++j) {
        ull kj = s_key[j];
        r += (int)((kj > k) || (kj == k && j < tid));
    }
    int o = b * SELN + r;
    int s = b * SELN + tid;
    ord_x1[o] = sel_x1[s]; ord_y1[o] = sel_y1[s];
    ord_x2[o] = sel_x2[s]; ord_y2[o] = sel_y2[s];
    ord_area[o] = sel_area[s]; ord_score[o] = sel_score[s];
    ord_cls[o] = sel_cls[s]; ord_idx[o] = sel_idx[s];
}

// =============== Kernel 4: suppression mask in rank space (word-major, symmetric) ===============
__global__ __launch_bounds__(256) void mask_kernel(const int* __restrict__ cnt_ws,
                                                   const float* __restrict__ ord_x1, const float* __restrict__ ord_y1,
                                                   const float* __restrict__ ord_x2, const float* __restrict__ ord_y2,
                                                   const float* __restrict__ ord_area,
                                                   ull* __restrict__ mask_ws) {
    __shared__ float ox1[SELN], oy1[SELN], ox2[SELN], oy2[SELN], oar[SELN];
    const int b = blockIdx.x >> 4;
    const int chunk = blockIdx.x & 15;
    const int tid = threadIdx.x;
    int cnt = cnt_ws[b]; if (cnt > SELN) cnt = SELN;
    for (int s = tid; s < SELN; s += 256) {
        ox1[s] = ord_x1[b * SELN + s]; oy1[s] = ord_y1[b * SELN + s];
        ox2[s] = ord_x2[b * SELN + s]; oy2[s] = ord_y2[b * SELN + s];
        oar[s] = ord_area[b * SELN + s];
    }
    __syncthreads();
    int i = chunk * 32 + (tid & 31);
    int w = tid >> 5;
    ull m = 0ull;
    if (i < cnt) {
        float ax1 = ox1[i], ay1 = oy1[i], ax2 = ox2[i], ay2 = oy2[i], aar = oar[i];
        int jb = w << 6;
        int jend = cnt - jb; if (jend > 64) jend = 64;
        for (int t = 0; t < jend; ++t) {
            int j = jb + t;
            bool s = (j != i) && iou_gt(ax1, ay1, ax2, ay2, aar,
                                        ox1[j], oy1[j], ox2[j], oy2[j], oar[j]);
            m |= (ull)s << t;
        }
    }
    mask_ws[b * (8 * SELN) + w * SELN + i] = m;
}

// =============== Kernel 5: Jacobi greedy fixpoint + outputs (one block/image) ===============
__global__ __launch_bounds__(1024) void resolve_kernel(
        const float* __restrict__ pred, const float* __restrict__ logits,
        const float* __restrict__ score_ws, const int* __restrict__ hist,
        const int* __restrict__ cnt_ws, const ull* __restrict__ mask_ws,
        const float* __restrict__ ord_x1, const float* __restrict__ ord_y1,
        const float* __restrict__ ord_x2, const float* __restrict__ ord_y2,
        const float* __restrict__ ord_area, const float* __restrict__ ord_score,
        const float* __restrict__ ord_cls, const int* __restrict__ ord_idx,
        float* __restrict__ out) {
    __shared__ ull s_m[8][SELN];                       // 32 KB, [w][i]
    __shared__ float s_x1[SELN], s_y1[SELN], s_x2[SELN], s_y2[SELN], s_ar[SELN];
    __shared__ float s_sc[SELN], s_cl[SELN];
    __shared__ int s_ix[SELN];
    __shared__ int s_keeprank[MAXDET];
    __shared__ float kx1[MAXDET], ky1[MAXDET], kx2[MAXDET], ky2[MAXDET], kar[MAXDET];
    __shared__ float ksc[MAXDET], kcl[MAXDET];
    __shared__ int kix[MAXDET];
    __shared__ int s_kc;

    const int b = blockIdx.x;
    const int tid = threadIdx.x;
    const int lane = tid & 63;
    const int wid = tid >> 6;
    const float* predb = pred + (size_t)b * NN * NSTR;
    const float* logb  = logits + (size_t)b * NN * NCLS;

    int cnt = cnt_ws[b]; if (cnt > SELN) cnt = SELN;

    for (int i = tid; i < 8 * SELN; i += 1024)
        (&s_m[0][0])[i] = mask_ws[b * (8 * SELN) + i];
    for (int s = tid; s < SELN; s += 1024) {
        s_x1[s] = ord_x1[b * SELN + s]; s_y1[s] = ord_y1[b * SELN + s];
        s_x2[s] = ord_x2[b * SELN + s]; s_y2[s] = ord_y2[b * SELN + s];
        s_ar[s] = ord_area[b * SELN + s]; s_sc[s] = ord_score[b * SELN + s];
        s_cl[s] = ord_cls[b * SELN + s]; s_ix[s] = ord_idx[b * SELN + s];
    }
    __syncthreads();

    // ---- Jacobi fixpoint on wave 0 ----
    if (wid == 0) {
        ull vm[8], kw[8];
#pragma unroll
        for (int r = 0; r < 8; ++r) {
            int lo = r << 6;
            vm[r] = (cnt >= lo + 64) ? ~0ull : (cnt > lo ? ((1ull << (cnt - lo)) - 1ull) : 0ull);
            kw[r] = vm[r];
        }
        ull lanemask_lt = (1ull << lane) - 1ull;   // lane 63: bits 0..62
        for (int round = 0; round < SELN; ++round) {
            ull nw[8];
#pragma unroll
            for (int r = 0; r < 8; ++r) {
                int i = (r << 6) + lane;
                ull supp = 0ull;
#pragma unroll
                for (int w = 0; w < 8; ++w) {
                    if (w < r) supp |= kw[w] & s_m[w][i];
                }
                supp |= kw[r] & s_m[r][i] & lanemask_lt;
                nw[r] = __ballot((int)(supp == 0ull)) & vm[r];
            }
            bool changed = false;
#pragma unroll
            for (int r = 0; r < 8; ++r) { changed |= (nw[r] != kw[r]); kw[r] = nw[r]; }
            if (!changed) break;
        }
        // compact kept ranks (parallel per lane)
        int totkept = 0;
#pragma unroll
        for (int r = 0; r < 8; ++r) totkept += __popcll(kw[r]);
        int kc = totkept < MAXDET ? totkept : MAXDET;
        int basер = 0;
#pragma unroll
        for (int r = 0; r < 8; ++r) {
            if ((kw[r] >> lane) & 1ull) {
                int pos = basер + (int)__popcll(kw[r] & lanemask_lt);
                if (pos < MAXDET) s_keeprank[pos] = (r << 6) + lane;
            }
            basер += (int)__popcll(kw[r]);
        }
        if (lane == 0) s_kc = kc;
    }
    __syncthreads();
    int kc = s_kc;

    // ---- fill kept arrays ----
    if (tid < kc) {
        int r = s_keeprank[tid];
        kx1[tid] = s_x1[r]; ky1[tid] = s_y1[r]; kx2[tid] = s_x2[r]; ky2[tid] = s_y2[r];
        kar[tid] = s_ar[r]; ksc[tid] = s_sc[r]; kcl[tid] = s_cl[r]; kix[tid] = s_ix[r];
    }
    __syncthreads();

    // ---- continuation (wave 0, only if <300 kept and unselected valid remain) ----
    if (wid == 0 && kc < MAXDET) {
        int total = 0;
#pragma unroll
        for (int k = 0; k < 16; ++k) total += hist[b * NBIN + lane * 16 + k];
#pragma unroll
        for (int d = 32; d >= 1; d >>= 1) total += __shfl_xor(total, d);
        if (total > cnt) {
            ull prevkey = (cnt > 0) ? (((ull)__float_as_uint(s_sc[cnt - 1]) << 32)
                                       | (unsigned int)(0xFFFFFFFFu - (unsigned int)s_ix[cnt - 1]))
                                    : ~0ull;
            const float* sb = score_ws + (size_t)b * NN;
            while (kc < MAXDET) {
                ull best = 0ull;
                for (int i0 = lane; i0 < NN; i0 += 64) {
                    float s = sb[i0];
                    if (s > 0.0f) {
                        ull key = ((ull)__float_as_uint(s) << 32)
                                  | (unsigned int)(0xFFFFFFFFu - (unsigned int)i0);
                        if (key < prevkey && key > best) best = key;
                    }
                }
#pragma unroll
                for (int d = 32; d >= 1; d >>= 1) {
                    ull o = __shfl_xor(best, d);
                    if (o > best) best = o;
                }
                if (best == 0ull) break;
                prevkey = best;
                int gi = (int)(0xFFFFFFFFu - (unsigned int)(best & 0xFFFFFFFFull));
                float sc = __uint_as_float((unsigned int)(best >> 32));
                const float* pp = predb + (size_t)gi * NSTR;
                float cx = pp[0], cy = pp[1], w = pp[2], h = pp[3];
                int c = cand_cls(pp);
                float off = (float)c * MAX_WH_C;
                float x1 = (cx - w * 0.5f) + off;
                float y1 = (cy - h * 0.5f) + off;
                float x2 = (cx + w * 0.5f) + off;
                float y2 = (cy + h * 0.5f) + off;
                float ar = (x2 - x1) * (y2 - y1);
                bool f = false;
                for (int t = lane; t < kc; t += 64)
                    if (iou_gt(kx1[t], ky1[t], kx2[t], ky2[t], kar[t], x1, y1, x2, y2, ar)) f = true;
                if (!__any((int)f)) {
                    if (lane == 0) {
                        kx1[kc] = x1; ky1[kc] = y1; kx2[kc] = x2; ky2[kc] = y2;
                        kar[kc] = ar; ksc[kc] = sc; kcl[kc] = (float)c; kix[kc] = gi;
                    }
                    kc++;
                }
            }
            if (lane == 0) s_kc = kc;
        }
    }
    __syncthreads();
    kc = s_kc;

    // ---- outputs (every element written every launch) ----
    if (tid < MAXDET) {
        int t = tid;
        float o0 = 0, o1 = 0, o2 = 0, o3 = 0, o4 = 0, o5 = 0;
        if (t < kc) {
            int idx = kix[t];
            const float* pp = predb + (size_t)idx * NSTR;
            float cx = pp[0], cy = pp[1], w = pp[2], h = pp[3];
            o0 = cx - w * 0.5f; o1 = cy - h * 0.5f;
            o2 = cx + w * 0.5f; o3 = cy + h * 0.5f;
            o4 = ksc[t];        o5 = kcl[t];
        }
        float* dd = out + (size_t)b * (MAXDET * 6) + (size_t)t * 6;
        dd[0] = o0; dd[1] = o1; dd[2] = o2; dd[3] = o3; dd[4] = o4; dd[5] = o5;
        out[(size_t)NB * MAXDET * 6 + (size_t)NB * MAXDET * NCLS + (size_t)b * MAXDET + t] =
            (t < kc) ? 1.0f : 0.0f;
    }
    float* lbase = out + (size_t)NB * MAXDET * 6 + (size_t)b * (MAXDET * NCLS);
    for (int t = wid; t < MAXDET; t += 16) {
        float* dst = lbase + (size_t)t * NCLS;
        if (t < kc) {
            const float* src = logb + (size_t)kix[t] * NCLS;
            for (int c = lane; c < NCLS; c += 64) dst[c] = src[c];
        } else {
            for (int c = lane; c < NCLS; c += 64) dst[c] = 0.0f;
        }
    }
}

// =============== Fallback: self-contained round-2 kernel (used only if ws too small) ===============
__global__ __launch_bounds__(1024) void fallback_kernel(const float* __restrict__ pred,
                                                        const float* __restrict__ logits,
                                                        float* __restrict__ out) {
    __shared__ ull s_keys[SORTN];
    __shared__ float sel_x1[SORTN], sel_y1[SORTN], sel_x2[SORTN], sel_y2[SORTN];
    __shared__ float sel_area[SORTN], sel_cls[SORTN];
    __shared__ int   sel_idx[SORTN];
    __shared__ float kx1[MAXDET], ky1[MAXDET], kx2[MAXDET], ky2[MAXDET], karea[MAXDET];
    __shared__ float kscore[MAXDET], kcls[MAXDET];
    __shared__ int   kidx[MAXDET];
    __shared__ int   s_hist[NBIN];
    __shared__ int   s_suppk[64];
    __shared__ unsigned int s_supmask[64][2];
    __shared__ int   s_kc, s_T, s_cnt;

    const int b = blockIdx.x;
    const int tid = threadIdx.x;
    const int lane = tid & 63;
    const int wid = tid >> 6;
    const float* predb = pred + (size_t)b * NN * NSTR;
    const float* logb  = logits + (size_t)b * NN * NCLS;

    int kc_total = 0;
    int prevT = NBIN;

    while (kc_total < MAXDET && prevT > 0) {
        s_hist[tid] = 0;
        if (tid == 0) { s_cnt = 0; s_T = NBIN; }
        __syncthreads();
        for (int i = tid; i < NN; i += 1024) {
            float s = cand_score(predb + (size_t)i * NSTR);
            if (s > 0.0f) {
                int bin = (int)((__float_as_uint(s) - BINBASE) >> BINSHIFT);
                if (bin < prevT) atomicAdd(&s_hist[bin], 1);
            }
        }
        __syncthreads();
        for (int d = 1; d < NBIN; d <<= 1) {
            int v = s_hist[tid] + ((tid + d < NBIN) ? s_hist[tid + d] : 0);
            __syncthreads();
            s_hist[tid] = v;
            __syncthreads();
        }
        if (s_hist[tid] <= SORTN) atomicMin(&s_T, tid);
        __syncthreads();
        int T = s_T;
        int rem_total = s_hist[0];
        if (T >= prevT) {
            if (rem_total == 0) { prevT = 0; break; }
            T = prevT - 1;
        }
        __syncthreads();
        for (int i = tid; i < NN; i += 1024) {
            float s = cand_score(predb + (size_t)i * NSTR);
            if (s > 0.0f) {
                int bin = (int)((__float_as_uint(s) - BINBASE) >> BINSHIFT);
                if (bin >= T && bin < prevT) {
                    int pos = atomicAdd(&s_cnt, 1);
                    if (pos < SORTN)
                        s_keys[pos] = ((ull)__float_as_uint(s) << 32)
                                      | (unsigned int)(0xFFFFFFFFu - (unsigned int)i);
                }
            }
        }
        __syncthreads();
        int cnt = s_cnt; if (cnt > SORTN) cnt = SORTN;
        int npow = 64; while (npow < cnt) npow <<= 1;
        for (int i = cnt + tid; i < npow; i += 1024) s_keys[i] = 0ull;
        __syncthreads();
        for (int k = 2; k <= npow; k <<= 1) {
            for (int j = k >> 1; j > 0; j >>= 1) {
                for (int idx = tid; idx < npow; idx += 1024) {
                    int p = idx ^ j;
                    if (p > idx) {
                        ull a = s_keys[idx], c = s_keys[p];
                        bool desc = ((idx & k) == 0);
                        if (desc ? (a < c) : (a > c)) { s_keys[idx] = c; s_keys[p] = a; }
                    }
                }
                __syncthreads();
            }
        }
        for (int t = tid; t < cnt; t += 1024) {
            ull key = s_keys[t];
            int i = (int)(0xFFFFFFFFu - (unsigned int)(key & 0xFFFFFFFFull));
            const float* p = predb + (size_t)i * NSTR;
            float cx = p[0], cy = p[1], w = p[2], h = p[3];
            int c = cand_cls(p);
            float off = (float)c * MAX_WH_C;
            float x1 = (cx - w * 0.5f) + off;
            float y1 = (cy - h * 0.5f) + off;
            float x2 = (cx + w * 0.5f) + off;
            float y2 = (cy + h * 0.5f) + off;
            sel_x1[t] = x1; sel_y1[t] = y1; sel_x2[t] = x2; sel_y2[t] = y2;
            sel_area[t] = (x2 - x1) * (y2 - y1);
            sel_cls[t] = (float)c;
            sel_idx[t] = i;
        }
        __syncthreads();
        int nb2 = (cnt + 63) >> 6;
        for (int batch = 0; batch < nb2; ++batch) {
            int kcb = kc_total;
            if (kcb >= MAXDET) break;
            if (tid < 64) { s_suppk[tid] = 0; s_supmask[tid][0] = 0u; s_supmask[tid][1] = 0u; }
            __syncthreads();

            int cloc = tid >> 4, ch = tid & 15;
            int gi = batch * 64 + cloc;
            bool validc = gi < cnt;
            float ax1 = 0, ay1 = 0, ax2 = 0, ay2 = 0, aar = 0;
            if (validc) {
                ax1 = sel_x1[gi]; ay1 = sel_y1[gi];
                ax2 = sel_x2[gi]; ay2 = sel_y2[gi]; aar = sel_area[gi];
            }
            bool flag = false;
            if (validc) {
                for (int t = ch; t < kcb; t += 16) {
                    if (iou_gt(kx1[t], ky1[t], kx2[t], ky2[t], karea[t],
                               ax1, ay1, ax2, ay2, aar)) flag = true;
                }
            }
            ull bal = __ballot((int)flag);
            if ((lane & 15) == 0) {
                unsigned int sub = (unsigned int)((bal >> (lane & 48)) & 0xFFFFull);
                s_suppk[cloc] = (sub != 0u);
            }
            unsigned int mbits = 0;
            if (validc) {
                for (int jj = 0; jj < 4; ++jj) {
                    int j = (ch << 2) + jj;
                    int gj = batch * 64 + j;
                    if (j > cloc && gj < cnt) {
                        if (iou_gt(ax1, ay1, ax2, ay2, aar,
                                   sel_x1[gj], sel_y1[gj], sel_x2[gj], sel_y2[gj], sel_area[gj]))
                            mbits |= 1u << (j & 31);
                    }
                }
            }
            if (mbits) atomicOr(&s_supmask[cloc][(ch >> 3) & 1], mbits);
            __syncthreads();

            if (wid == 0) {
                ull mask = ((ull)s_supmask[lane][1] << 32) | s_supmask[lane][0];
                bool validj = (batch * 64 + lane) < cnt;
                ull rem = __ballot((int)(validj && (s_suppk[lane] == 0)));
                ull keepbits = 0;
                int kcount = kcb;
                while (rem && kcount < MAXDET) {
                    int i = __builtin_ctzll(rem);
                    rem &= rem - 1;
                    keepbits |= 1ull << i;
                    ++kcount;
                    ull mi = __shfl(mask, i);
                    rem &= ~mi;
                }
                if ((keepbits >> lane) & 1ull) {
                    int pos = kcb + __popcll(keepbits & ((1ull << lane) - 1ull));
                    int g2 = batch * 64 + lane;
                    kx1[pos] = sel_x1[g2]; ky1[pos] = sel_y1[g2];
                    kx2[pos] = sel_x2[g2]; ky2[pos] = sel_y2[g2];
                    karea[pos] = sel_area[g2];
                    kcls[pos] = sel_cls[g2]; kidx[pos] = sel_idx[g2];
                    kscore[pos] = __uint_as_float((unsigned int)(s_keys[g2] >> 32));
                }
                if (lane == 0) s_kc = kcount;
            }
            __syncthreads();
            kc_total = s_kc;
            __syncthreads();
        }
        prevT = T;
    }

    __syncthreads();
    int kc = kc_total;
    if (tid < MAXDET) {
        int t = tid;
        float o0 = 0, o1 = 0, o2 = 0, o3 = 0, o4 = 0, o5 = 0;
        if (t < kc) {
            int idx = kidx[t];
            const float* pp = predb + (size_t)idx * NSTR;
            float cx = pp[0], cy = pp[1], w = pp[2], h = pp[3];
            o0 = cx - w * 0.5f; o1 = cy - h * 0.5f;
            o2 = cx + w * 0.5f; o3 = cy + h * 0.5f;
            o4 = kscore[t];     o5 = kcls[t];
        }
        float* dd = out + (size_t)b * (MAXDET * 6) + (size_t)t * 6;
        dd[0] = o0; dd[1] = o1; dd[2] = o2; dd[3] = o3; dd[4] = o4; dd[5] = o5;
        out[(size_t)NB * MAXDET * 6 + (size_t)NB * MAXDET * NCLS + (size_t)b * MAXDET + t] =
            (t < kc) ? 1.0f : 0.0f;
    }
    float* lbase = out + (size_t)NB * MAXDET * 6 + (size_t)b * (MAXDET * NCLS);
    for (int t = wid; t < MAXDET; t += 16) {
        float* dst = lbase + (size_t)t * NCLS;
        if (t < kc) {
            const float* src = logb + (size_t)kidx[t] * NCLS;
            for (int c = lane; c < NCLS; c += 64) dst[c] = src[c];
        } else {
            for (int c = lane; c < NCLS; c += 64) dst[c] = 0.0f;
        }
    }
}

extern "C" void kernel_launch(void* const* d_in, const int* in_sizes, int n_in,
                              void* d_out, int out_size, void* d_ws, size_t ws_size,
                              hipStream_t stream) {
    const float* pred   = (const float*)d_in[0];
    const float* logits = (const float*)d_in[1];
    float* out = (float*)d_out;

    // ws layout (all offsets 8B-aligned)
    const size_t off_hist = 0;                          // 8*1024*4 = 32768
    const size_t off_cnt  = 32768;                      // 8*4 = 32
    const size_t off_key  = 32800;                      // 8*512*8 = 32768
    const size_t off_sel  = 65568;                      // 8 arrays * 16384 = 131072
    const size_t off_ord  = off_sel + 8 * 16384;        // 196640; 8 arrays * 16384
    const size_t off_mask = off_ord + 8 * 16384;        // 327712; 8*4096*8 = 262144
    const size_t off_sws  = off_mask + 262144;          // 589856; 8*25200*4 = 806400
    const size_t need     = off_sws + (size_t)NB * NN * 4;   // 1,396,256

    if (d_ws == nullptr || ws_size < need) {
        fallback_kernel<<<NB, 1024, 0, stream>>>(pred, logits, out);
        return;
    }

    char* ws = (char*)d_ws;
    int* hist = (int*)(ws + off_hist);
    int* cnt_ws = (int*)(ws + off_cnt);
    ull* sel_key = (ull*)(ws + off_key);
    float* sel_x1 = (float*)(ws + off_sel);
    float* sel_y1 = sel_x1 + NB * SELN;
    float* sel_x2 = sel_y1 + NB * SELN;
    float* sel_y2 = sel_x2 + NB * SELN;
    float* sel_area = sel_y2 + NB * SELN;
    float* sel_score = sel_area + NB * SELN;
    float* sel_cls = sel_score + NB * SELN;
    int*   sel_idx = (int*)(sel_cls + NB * SELN);
    float* ord_x1 = (float*)(ws + off_ord);
    float* ord_y1 = ord_x1 + NB * SELN;
    float* ord_x2 = ord_y1 + NB * SELN;
    float* ord_y2 = ord_x2 + NB * SELN;
    float* ord_area = ord_y2 + NB * SELN;
    float* ord_score = ord_area + NB * SELN;
    float* ord_cls = ord_score + NB * SELN;
    int*   ord_idx = (int*)(ord_cls + NB * SELN);
    ull* mask_ws = (ull*)(ws + off_mask);
    float* score_ws = (float*)(ws + off_sws);

    hipMemsetAsync(ws, 0, off_key, stream);   // zero hist + counters

    prep_kernel<<<(NB * NN) / PREP_ROWS, 256, 0, stream>>>(pred, score_ws, hist);
    select_kernel<<<NB * BPI, 256, 0, stream>>>(pred, score_ws, hist, cnt_ws,
                                                sel_key, sel_x1, sel_y1, sel_x2, sel_y2,
                                                sel_area, sel_score, sel_cls, sel_idx);
    rank_kernel<<<NB, 512, 0, stream>>>(cnt_ws, sel_key, sel_x1, sel_y1, sel_x2, sel_y2,
                                        sel_area, sel_score, sel_cls, sel_idx,
                                        ord_x1, ord_y1, ord_x2, ord_y2,
                                        ord_area, ord_score, ord_cls, ord_idx);
    mask_kernel<<<NB * 16, 256, 0, stream>>>(cnt_ws, ord_x1, ord_y1, ord_x2, ord_y2,
                                             ord_area, mask_ws);
    resolve_kernel<<<NB, 1024, 0, stream>>>(pred, logits, score_ws, hist, cnt_ws, mask_ws,
                                            ord_x1, ord_y1, ord_x2, ord_y2,
                                            ord_area, ord_score, ord_cls, ord_idx, out);
}

// Round 5
// 117.987 us; speedup vs baseline: 1.9544x; 1.0043x over previous
//
#include <hip/hip_runtime.h>

#pragma clang fp contract(off)

#define NB 8
#define NN 25200
#define NCLS 80
#define NSTR 85
#define MAXDET 300
#define CONF_T 0.4f
#define IOU_T 0.45f
#define MAX_WH_C 4096.0f

#define NBIN 1024
#define BINSHIFT 14
#define BINBASE 0x3EC00000u   // bits(0.375) < bits of any valid score (>0.4)
#define SELN 512
#define BPI 99                // select blocks per image: 99*256 >= 25200
#define SORTN 2048            // fallback kernel only

typedef unsigned long long ull;

// ---------------- helpers ----------------
__device__ __forceinline__ float cand_score(const float* __restrict__ p) {
    float obj = p[4];
    float best = p[5] * obj;
    for (int j = 1; j < NCLS; ++j) {
        float s = p[5 + j] * obj;
        if (s > best) best = s;
    }
    return ((obj > CONF_T) && (best > CONF_T)) ? best : -1.0f;
}
__device__ __forceinline__ int cand_cls(const float* __restrict__ p) {
    float obj = p[4];
    float best = p[5] * obj; int bc = 0;
    for (int j = 1; j < NCLS; ++j) {
        float s = p[5 + j] * obj;
        if (s > best) { best = s; bc = j; }   // strict >: first-index argmax
    }
    return bc;
}
__device__ __forceinline__ bool iou_gt(float ax1, float ay1, float ax2, float ay2, float aarea,
                                       float bx1, float by1, float bx2, float by2, float barea) {
    float lx = fmaxf(ax1, bx1);
    float ly = fmaxf(ay1, by1);
    float rx = fminf(ax2, bx2);
    float ry = fminf(ay2, by2);
    float iw = fmaxf(rx - lx, 0.0f);
    float ih = fmaxf(ry - ly, 0.0f);
    float inter = iw * ih;
    float iou = inter / ((aarea + barea - inter) + 1e-9f);
    return iou > IOU_T;
}

// =============== Kernel 0: zero hist + counters (replaces pathological runtime fill) ===============
__global__ __launch_bounds__(256) void zero_kernel(int* __restrict__ p, int n) {
    int i = blockIdx.x * 256 + threadIdx.x;
    if (i < n) p[i] = 0;
}

// =============== Kernel 1: score + global histogram (float4 LDS staging) ===============
#define PREP_ROWS 64
__global__ __launch_bounds__(256) void prep_kernel(const float* __restrict__ pred,
                                                   float* __restrict__ score_ws,
                                                   int* __restrict__ hist) {
    __shared__ float st[PREP_ROWS * NSTR];   // 21760 B = 1360 float4
    const int R0 = blockIdx.x * PREP_ROWS;
    const float4* src = reinterpret_cast<const float4*>(pred + (size_t)R0 * NSTR);
    float4* dst4 = reinterpret_cast<float4*>(st);
    const int tid = threadIdx.x;
    for (int i = tid; i < PREP_ROWS * NSTR / 4; i += 256) dst4[i] = src[i];
    __syncthreads();

    int row = tid >> 2, part = tid & 3;
    const float* pr = st + row * NSTR;
    float obj = pr[4];
    float best = -1.0f; int bc = part * 20;
    const float* pc = pr + 5 + part * 20;
#pragma unroll
    for (int k = 0; k < 20; ++k) {
        float s = pc[k] * obj;
        if (s > best) { best = s; bc = part * 20 + k; }
    }
#pragma unroll
    for (int d = 1; d <= 2; d <<= 1) {
        float ob = __shfl_xor(best, d);
        int   oc = __shfl_xor(bc, d);
        if (ob > best || (ob == best && oc < bc)) { best = ob; bc = oc; }
    }
    if (part == 0) {
        int grow = R0 + row;
        bool valid = (obj > CONF_T) && (best > CONF_T);
        score_ws[grow] = valid ? best : -1.0f;
        if (valid) {
            int ib = grow / NN;
            int bin = (int)((__float_as_uint(best) - BINBASE) >> BINSHIFT);
            atomicAdd(&hist[ib * NBIN + bin], 1);
        }
    }
}

// =============== Kernel 2: threshold + compact selected list (cls recomputed) ===============
__global__ __launch_bounds__(256) void select_kernel(const float* __restrict__ pred,
                                                     const float* __restrict__ score_ws,
                                                     const int* __restrict__ hist,
                                                     int* __restrict__ cnt_ws,
                                                     ull* __restrict__ sel_key,
                                                     float* __restrict__ sel_x1, float* __restrict__ sel_y1,
                                                     float* __restrict__ sel_x2, float* __restrict__ sel_y2,
                                                     float* __restrict__ sel_area, float* __restrict__ sel_score,
                                                     float* __restrict__ sel_cls, int* __restrict__ sel_idx) {
    __shared__ int sT;
    const int ib = blockIdx.x / BPI;
    const int tid = threadIdx.x;
    if (tid < 64) {
        int lane = tid;
        int acc = 0; int S[16];
#pragma unroll
        for (int k = 15; k >= 0; --k) { acc += hist[ib * NBIN + lane * 16 + k]; S[k] = acc; }
        int tot = acc;
        int incl = tot;
#pragma unroll
        for (int d = 1; d < 64; d <<= 1) {
            int v = __shfl_down(incl, d);
            if (lane + d < 64) incl += v;
        }
        int E = incl - tot;   // sum over lanes > lane
        int Tl = NBIN;
#pragma unroll
        for (int k = 0; k < 16; ++k)
            if (Tl == NBIN && S[k] + E <= SELN) Tl = lane * 16 + k;
#pragma unroll
        for (int d = 1; d < 64; d <<= 1) {
            int o = __shfl_xor(Tl, d);
            if (o < Tl) Tl = o;
        }
        if (tid == 0) sT = Tl;
    }
    __syncthreads();
    int T = sT;
    int g = (blockIdx.x % BPI) * 256 + tid;
    if (g < NN) {
        float s = score_ws[(size_t)ib * NN + g];
        if (s > 0.0f) {
            int bin = (int)((__float_as_uint(s) - BINBASE) >> BINSHIFT);
            if (bin >= T) {
                int pos = atomicAdd(&cnt_ws[ib], 1);
                if (pos < SELN) {
                    int o = ib * SELN + pos;
                    const float* p = pred + ((size_t)ib * NN + g) * NSTR;
                    float cx = p[0], cy = p[1], w = p[2], h = p[3];
                    int c = cand_cls(p);
                    float off = (float)c * MAX_WH_C;
                    float x1 = (cx - w * 0.5f) + off;
                    float y1 = (cy - h * 0.5f) + off;
                    float x2 = (cx + w * 0.5f) + off;
                    float y2 = (cy + h * 0.5f) + off;
                    sel_key[o] = ((ull)__float_as_uint(s) << 32)
                                 | (unsigned int)(0xFFFFFFFFu - (unsigned int)g);
                    sel_x1[o] = x1; sel_y1[o] = y1; sel_x2[o] = x2; sel_y2[o] = y2;
                    sel_area[o] = (x2 - x1) * (y2 - y1);
                    sel_score[o] = s; sel_cls[o] = (float)c; sel_idx[o] = g;
                }
            }
        }
    }
}

// =============== Kernel 3: rank by counting + scatter to rank-ordered arrays ===============
__global__ __launch_bounds__(512) void rank_kernel(const int* __restrict__ cnt_ws,
                                                   const ull* __restrict__ sel_key,
                                                   const float* __restrict__ sel_x1, const float* __restrict__ sel_y1,
                                                   const float* __restrict__ sel_x2, const float* __restrict__ sel_y2,
                                                   const float* __restrict__ sel_area, const float* __restrict__ sel_score,
                                                   const float* __restrict__ sel_cls, const int* __restrict__ sel_idx,
                                                   float* __restrict__ ord_x1, float* __restrict__ ord_y1,
                                                   float* __restrict__ ord_x2, float* __restrict__ ord_y2,
                                                   float* __restrict__ ord_area, float* __restrict__ ord_score,
                                                   float* __restrict__ ord_cls, int* __restrict__ ord_idx) {
    __shared__ ull s_key[SELN];
    const int b = blockIdx.x;
    const int tid = threadIdx.x;
    int cnt = cnt_ws[b]; if (cnt > SELN) cnt = SELN;
    s_key[tid] = (tid < cnt) ? sel_key[b * SELN + tid] : 0ull;
    __syncthreads();
    ull k = s_key[tid];
    int r = 0;
    for (int j = 0; j < SELN; ++j) {
        ull kj = s_key[j];
        r += (int)((kj > k) || (kj == k && j < tid));
    }
    int o = b * SELN + r;
    int s = b * SELN + tid;
    ord_x1[o] = sel_x1[s]; ord_y1[o] = sel_y1[s];
    ord_x2[o] = sel_x2[s]; ord_y2[o] = sel_y2[s];
    ord_area[o] = sel_area[s]; ord_score[o] = sel_score[s];
    ord_cls[o] = sel_cls[s]; ord_idx[o] = sel_idx[s];
}

// =============== Kernel 4: suppression mask in rank space (word-major, symmetric) ===============
__global__ __launch_bounds__(256) void mask_kernel(const int* __restrict__ cnt_ws,
                                                   const float* __restrict__ ord_x1, const float* __restrict__ ord_y1,
                                                   const float* __restrict__ ord_x2, const float* __restrict__ ord_y2,
                                                   const float* __restrict__ ord_area,
                                                   ull* __restrict__ mask_ws) {
    __shared__ float ox1[SELN], oy1[SELN], ox2[SELN], oy2[SELN], oar[SELN];
    const int b = blockIdx.x >> 4;
    const int chunk = blockIdx.x & 15;
    const int tid = threadIdx.x;
    int cnt = cnt_ws[b]; if (cnt > SELN) cnt = SELN;
    for (int s = tid; s < SELN; s += 256) {
        ox1[s] = ord_x1[b * SELN + s]; oy1[s] = ord_y1[b * SELN + s];
        ox2[s] = ord_x2[b * SELN + s]; oy2[s] = ord_y2[b * SELN + s];
        oar[s] = ord_area[b * SELN + s];
    }
    __syncthreads();
    int i = chunk * 32 + (tid & 31);
    int w = tid >> 5;
    ull m = 0ull;
    if (i < cnt) {
        float ax1 = ox1[i], ay1 = oy1[i], ax2 = ox2[i], ay2 = oy2[i], aar = oar[i];
        int jb = w << 6;
        int jend = cnt - jb; if (jend > 64) jend = 64;
        for (int t = 0; t < jend; ++t) {
            int j = jb + t;
            bool s = (j != i) && iou_gt(ax1, ay1, ax2, ay2, aar,
                                        ox1[j], oy1[j], ox2[j], oy2[j], oar[j]);
            m |= (ull)s << t;
        }
    }
    mask_ws[b * (8 * SELN) + w * SELN + i] = m;
}

// =============== Kernel 5: Jacobi greedy fixpoint + outputs (one block/image) ===============
__global__ __launch_bounds__(1024) void resolve_kernel(
        const float* __restrict__ pred, const float* __restrict__ logits,
        const float* __restrict__ score_ws, const int* __restrict__ hist,
        const int* __restrict__ cnt_ws, const ull* __restrict__ mask_ws,
        const float* __restrict__ ord_x1, const float* __restrict__ ord_y1,
        const float* __restrict__ ord_x2, const float* __restrict__ ord_y2,
        const float* __restrict__ ord_area, const float* __restrict__ ord_score,
        const float* __restrict__ ord_cls, const int* __restrict__ ord_idx,
        float* __restrict__ out) {
    __shared__ ull s_m[8][SELN];                       // 32 KB, [w][i]
    __shared__ float s_x1[SELN], s_y1[SELN], s_x2[SELN], s_y2[SELN], s_ar[SELN];
    __shared__ float s_sc[SELN], s_cl[SELN];
    __shared__ int s_ix[SELN];
    __shared__ int s_keeprank[MAXDET];
    __shared__ float kx1[MAXDET], ky1[MAXDET], kx2[MAXDET], ky2[MAXDET], kar[MAXDET];
    __shared__ float ksc[MAXDET], kcl[MAXDET];
    __shared__ int kix[MAXDET];
    __shared__ int s_kc;

    const int b = blockIdx.x;
    const int tid = threadIdx.x;
    const int lane = tid & 63;
    const int wid = tid >> 6;
    const float* predb = pred + (size_t)b * NN * NSTR;
    const float* logb  = logits + (size_t)b * NN * NCLS;

    int cnt = cnt_ws[b]; if (cnt > SELN) cnt = SELN;

    for (int i = tid; i < 8 * SELN; i += 1024)
        (&s_m[0][0])[i] = mask_ws[b * (8 * SELN) + i];
    for (int s = tid; s < SELN; s += 1024) {
        s_x1[s] = ord_x1[b * SELN + s]; s_y1[s] = ord_y1[b * SELN + s];
        s_x2[s] = ord_x2[b * SELN + s]; s_y2[s] = ord_y2[b * SELN + s];
        s_ar[s] = ord_area[b * SELN + s]; s_sc[s] = ord_score[b * SELN + s];
        s_cl[s] = ord_cls[b * SELN + s]; s_ix[s] = ord_idx[b * SELN + s];
    }
    __syncthreads();

    // ---- Jacobi fixpoint on wave 0 ----
    if (wid == 0) {
        ull vm[8], kw[8];
#pragma unroll
        for (int r = 0; r < 8; ++r) {
            int lo = r << 6;
            vm[r] = (cnt >= lo + 64) ? ~0ull : (cnt > lo ? ((1ull << (cnt - lo)) - 1ull) : 0ull);
            kw[r] = vm[r];
        }
        ull lanemask_lt = (1ull << lane) - 1ull;   // lane 63: bits 0..62
        for (int round = 0; round < SELN; ++round) {
            ull nw[8];
#pragma unroll
            for (int r = 0; r < 8; ++r) {
                int i = (r << 6) + lane;
                ull supp = 0ull;
#pragma unroll
                for (int w = 0; w < 8; ++w) {
                    if (w < r) supp |= kw[w] & s_m[w][i];
                }
                supp |= kw[r] & s_m[r][i] & lanemask_lt;
                nw[r] = __ballot((int)(supp == 0ull)) & vm[r];
            }
            bool changed = false;
#pragma unroll
            for (int r = 0; r < 8; ++r) { changed |= (nw[r] != kw[r]); kw[r] = nw[r]; }
            if (!changed) break;
        }
        // compact kept ranks (parallel per lane)
        int totkept = 0;
#pragma unroll
        for (int r = 0; r < 8; ++r) totkept += __popcll(kw[r]);
        int kc = totkept < MAXDET ? totkept : MAXDET;
        int basep = 0;
#pragma unroll
        for (int r = 0; r < 8; ++r) {
            if ((kw[r] >> lane) & 1ull) {
                int pos = basep + (int)__popcll(kw[r] & lanemask_lt);
                if (pos < MAXDET) s_keeprank[pos] = (r << 6) + lane;
            }
            basep += (int)__popcll(kw[r]);
        }
        if (lane == 0) s_kc = kc;
    }
    __syncthreads();
    int kc = s_kc;

    // ---- fill kept arrays ----
    if (tid < kc) {
        int r = s_keeprank[tid];
        kx1[tid] = s_x1[r]; ky1[tid] = s_y1[r]; kx2[tid] = s_x2[r]; ky2[tid] = s_y2[r];
        kar[tid] = s_ar[r]; ksc[tid] = s_sc[r]; kcl[tid] = s_cl[r]; kix[tid] = s_ix[r];
    }
    __syncthreads();

    // ---- continuation (wave 0, only if <300 kept and unselected valid remain) ----
    if (wid == 0 && kc < MAXDET) {
        int total = 0;
#pragma unroll
        for (int k = 0; k < 16; ++k) total += hist[b * NBIN + lane * 16 + k];
#pragma unroll
        for (int d = 32; d >= 1; d >>= 1) total += __shfl_xor(total, d);
        if (total > cnt) {
            ull prevkey = (cnt > 0) ? (((ull)__float_as_uint(s_sc[cnt - 1]) << 32)
                                       | (unsigned int)(0xFFFFFFFFu - (unsigned int)s_ix[cnt - 1]))
                                    : ~0ull;
            const float* sb = score_ws + (size_t)b * NN;
            while (kc < MAXDET) {
                ull best = 0ull;
                for (int i0 = lane; i0 < NN; i0 += 64) {
                    float s = sb[i0];
                    if (s > 0.0f) {
                        ull key = ((ull)__float_as_uint(s) << 32)
                                  | (unsigned int)(0xFFFFFFFFu - (unsigned int)i0);
                        if (key < prevkey && key > best) best = key;
                    }
                }
#pragma unroll
                for (int d = 32; d >= 1; d >>= 1) {
                    ull o = __shfl_xor(best, d);
                    if (o > best) best = o;
                }
                if (best == 0ull) break;
                prevkey = best;
                int gi = (int)(0xFFFFFFFFu - (unsigned int)(best & 0xFFFFFFFFull));
                float sc = __uint_as_float((unsigned int)(best >> 32));
                const float* pp = predb + (size_t)gi * NSTR;
                float cx = pp[0], cy = pp[1], w = pp[2], h = pp[3];
                int c = cand_cls(pp);
                float off = (float)c * MAX_WH_C;
                float x1 = (cx - w * 0.5f) + off;
                float y1 = (cy - h * 0.5f) + off;
                float x2 = (cx + w * 0.5f) + off;
                float y2 = (cy + h * 0.5f) + off;
                float ar = (x2 - x1) * (y2 - y1);
                bool f = false;
                for (int t = lane; t < kc; t += 64)
                    if (iou_gt(kx1[t], ky1[t], kx2[t], ky2[t], kar[t], x1, y1, x2, y2, ar)) f = true;
                if (!__any((int)f)) {
                    if (lane == 0) {
                        kx1[kc] = x1; ky1[kc] = y1; kx2[kc] = x2; ky2[kc] = y2;
                        kar[kc] = ar; ksc[kc] = sc; kcl[kc] = (float)c; kix[kc] = gi;
                    }
                    kc++;
                }
            }
            if (lane == 0) s_kc = kc;
        }
    }
    __syncthreads();
    kc = s_kc;

    // ---- outputs (every element written every launch) ----
    if (tid < MAXDET) {
        int t = tid;
        float o0 = 0, o1 = 0, o2 = 0, o3 = 0, o4 = 0, o5 = 0;
        if (t < kc) {
            int idx = kix[t];
            const float* pp = predb + (size_t)idx * NSTR;
            float cx = pp[0], cy = pp[1], w = pp[2], h = pp[3];
            o0 = cx - w * 0.5f; o1 = cy - h * 0.5f;
            o2 = cx + w * 0.5f; o3 = cy + h * 0.5f;
            o4 = ksc[t];        o5 = kcl[t];
        }
        float* dd = out + (size_t)b * (MAXDET * 6) + (size_t)t * 6;
        dd[0] = o0; dd[1] = o1; dd[2] = o2; dd[3] = o3; dd[4] = o4; dd[5] = o5;
        out[(size_t)NB * MAXDET * 6 + (size_t)NB * MAXDET * NCLS + (size_t)b * MAXDET + t] =
            (t < kc) ? 1.0f : 0.0f;
    }
    float* lbase = out + (size_t)NB * MAXDET * 6 + (size_t)b * (MAXDET * NCLS);
    for (int t = wid; t < MAXDET; t += 16) {
        float* dst = lbase + (size_t)t * NCLS;
        if (t < kc) {
            const float* src = logb + (size_t)kix[t] * NCLS;
            for (int c = lane; c < NCLS; c += 64) dst[c] = src[c];
        } else {
            for (int c = lane; c < NCLS; c += 64) dst[c] = 0.0f;
        }
    }
}

// =============== Fallback: self-contained round-2 kernel (used only if ws too small) ===============
__global__ __launch_bounds__(1024) void fallback_kernel(const float* __restrict__ pred,
                                                        const float* __restrict__ logits,
                                                        float* __restrict__ out) {
    __shared__ ull s_keys[SORTN];
    __shared__ float sel_x1[SORTN], sel_y1[SORTN], sel_x2[SORTN], sel_y2[SORTN];
    __shared__ float sel_area[SORTN], sel_cls[SORTN];
    __shared__ int   sel_idx[SORTN];
    __shared__ float kx1[MAXDET], ky1[MAXDET], kx2[MAXDET], ky2[MAXDET], karea[MAXDET];
    __shared__ float kscore[MAXDET], kcls[MAXDET];
    __shared__ int   kidx[MAXDET];
    __shared__ int   s_hist[NBIN];
    __shared__ int   s_suppk[64];
    __shared__ unsigned int s_supmask[64][2];
    __shared__ int   s_kc, s_T, s_cnt;

    const int b = blockIdx.x;
    const int tid = threadIdx.x;
    const int lane = tid & 63;
    const int wid = tid >> 6;
    const float* predb = pred + (size_t)b * NN * NSTR;
    const float* logb  = logits + (size_t)b * NN * NCLS;

    int kc_total = 0;
    int prevT = NBIN;

    while (kc_total < MAXDET && prevT > 0) {
        s_hist[tid] = 0;
        if (tid == 0) { s_cnt = 0; s_T = NBIN; }
        __syncthreads();
        for (int i = tid; i < NN; i += 1024) {
            float s = cand_score(predb + (size_t)i * NSTR);
            if (s > 0.0f) {
                int bin = (int)((__float_as_uint(s) - BINBASE) >> BINSHIFT);
                if (bin < prevT) atomicAdd(&s_hist[bin], 1);
            }
        }
        __syncthreads();
        for (int d = 1; d < NBIN; d <<= 1) {
            int v = s_hist[tid] + ((tid + d < NBIN) ? s_hist[tid + d] : 0);
            __syncthreads();
            s_hist[tid] = v;
            __syncthreads();
        }
        if (s_hist[tid] <= SORTN) atomicMin(&s_T, tid);
        __syncthreads();
        int T = s_T;
        int rem_total = s_hist[0];
        if (T >= prevT) {
            if (rem_total == 0) { prevT = 0; break; }
            T = prevT - 1;
        }
        __syncthreads();
        for (int i = tid; i < NN; i += 1024) {
            float s = cand_score(predb + (size_t)i * NSTR);
            if (s > 0.0f) {
                int bin = (int)((__float_as_uint(s) - BINBASE) >> BINSHIFT);
                if (bin >= T && bin < prevT) {
                    int pos = atomicAdd(&s_cnt, 1);
                    if (pos < SORTN)
                        s_keys[pos] = ((ull)__float_as_uint(s) << 32)
                                      | (unsigned int)(0xFFFFFFFFu - (unsigned int)i);
                }
            }
        }
        __syncthreads();
        int cnt = s_cnt; if (cnt > SORTN) cnt = SORTN;
        int npow = 64; while (npow < cnt) npow <<= 1;
        for (int i = cnt + tid; i < npow; i += 1024) s_keys[i] = 0ull;
        __syncthreads();
        for (int k = 2; k <= npow; k <<= 1) {
            for (int j = k >> 1; j > 0; j >>= 1) {
                for (int idx = tid; idx < npow; idx += 1024) {
                    int p = idx ^ j;
                    if (p > idx) {
                        ull a = s_keys[idx], c = s_keys[p];
                        bool desc = ((idx & k) == 0);
                        if (desc ? (a < c) : (a > c)) { s_keys[idx] = c; s_keys[p] = a; }
                    }
                }
                __syncthreads();
            }
        }
        for (int t = tid; t < cnt; t += 1024) {
            ull key = s_keys[t];
            int i = (int)(0xFFFFFFFFu - (unsigned int)(key & 0xFFFFFFFFull));
            const float* p = predb + (size_t)i * NSTR;
            float cx = p[0], cy = p[1], w = p[2], h = p[3];
            int c = cand_cls(p);
            float off = (float)c * MAX_WH_C;
            float x1 = (cx - w * 0.5f) + off;
            float y1 = (cy - h * 0.5f) + off;
            float x2 = (cx + w * 0.5f) + off;
            float y2 = (cy + h * 0.5f) + off;
            sel_x1[t] = x1; sel_y1[t] = y1; sel_x2[t] = x2; sel_y2[t] = y2;
            sel_area[t] = (x2 - x1) * (y2 - y1);
            sel_cls[t] = (float)c;
            sel_idx[t] = i;
        }
        __syncthreads();
        int nb2 = (cnt + 63) >> 6;
        for (int batch = 0; batch < nb2; ++batch) {
            int kcb = kc_total;
            if (kcb >= MAXDET) break;
            if (tid < 64) { s_suppk[tid] = 0; s_supmask[tid][0] = 0u; s_supmask[tid][1] = 0u; }
            __syncthreads();

            int cloc = tid >> 4, ch = tid & 15;
            int gi = batch * 64 + cloc;
            bool validc = gi < cnt;
            float ax1 = 0, ay1 = 0, ax2 = 0, ay2 = 0, aar = 0;
            if (validc) {
                ax1 = sel_x1[gi]; ay1 = sel_y1[gi];
                ax2 = sel_x2[gi]; ay2 = sel_y2[gi]; aar = sel_area[gi];
            }
            bool flag = false;
            if (validc) {
                for (int t = ch; t < kcb; t += 16) {
                    if (iou_gt(kx1[t], ky1[t], kx2[t], ky2[t], karea[t],
                               ax1, ay1, ax2, ay2, aar)) flag = true;
                }
            }
            ull bal = __ballot((int)flag);
            if ((lane & 15) == 0) {
                unsigned int sub = (unsigned int)((bal >> (lane & 48)) & 0xFFFFull);
                s_suppk[cloc] = (sub != 0u);
            }
            unsigned int mbits = 0;
            if (validc) {
                for (int jj = 0; jj < 4; ++jj) {
                    int j = (ch << 2) + jj;
                    int gj = batch * 64 + j;
                    if (j > cloc && gj < cnt) {
                        if (iou_gt(ax1, ay1, ax2, ay2, aar,
                                   sel_x1[gj], sel_y1[gj], sel_x2[gj], sel_y2[gj], sel_area[gj]))
                            mbits |= 1u << (j & 31);
                    }
                }
            }
            if (mbits) atomicOr(&s_supmask[cloc][(ch >> 3) & 1], mbits);
            __syncthreads();

            if (wid == 0) {
                ull mask = ((ull)s_supmask[lane][1] << 32) | s_supmask[lane][0];
                bool validj = (batch * 64 + lane) < cnt;
                ull rem = __ballot((int)(validj && (s_suppk[lane] == 0)));
                ull keepbits = 0;
                int kcount = kcb;
                while (rem && kcount < MAXDET) {
                    int i = __builtin_ctzll(rem);
                    rem &= rem - 1;
                    keepbits |= 1ull << i;
                    ++kcount;
                    ull mi = __shfl(mask, i);
                    rem &= ~mi;
                }
                if ((keepbits >> lane) & 1ull) {
                    int pos = kcb + __popcll(keepbits & ((1ull << lane) - 1ull));
                    int g2 = batch * 64 + lane;
                    kx1[pos] = sel_x1[g2]; ky1[pos] = sel_y1[g2];
                    kx2[pos] = sel_x2[g2]; ky2[pos] = sel_y2[g2];
                    karea[pos] = sel_area[g2];
                    kcls[pos] = sel_cls[g2]; kidx[pos] = sel_idx[g2];
                    kscore[pos] = __uint_as_float((unsigned int)(s_keys[g2] >> 32));
                }
                if (lane == 0) s_kc = kcount;
            }
            __syncthreads();
            kc_total = s_kc;
            __syncthreads();
        }
        prevT = T;
    }

    __syncthreads();
    int kc = kc_total;
    if (tid < MAXDET) {
        int t = tid;
        float o0 = 0, o1 = 0, o2 = 0, o3 = 0, o4 = 0, o5 = 0;
        if (t < kc) {
            int idx = kidx[t];
            const float* pp = predb + (size_t)idx * NSTR;
            float cx = pp[0], cy = pp[1], w = pp[2], h = pp[3];
            o0 = cx - w * 0.5f; o1 = cy - h * 0.5f;
            o2 = cx + w * 0.5f; o3 = cy + h * 0.5f;
            o4 = kscore[t];     o5 = kcls[t];
        }
        float* dd = out + (size_t)b * (MAXDET * 6) + (size_t)t * 6;
        dd[0] = o0; dd[1] = o1; dd[2] = o2; dd[3] = o3; dd[4] = o4; dd[5] = o5;
        out[(size_t)NB * MAXDET * 6 + (size_t)NB * MAXDET * NCLS + (size_t)b * MAXDET + t] =
            (t < kc) ? 1.0f : 0.0f;
    }
    float* lbase = out + (size_t)NB * MAXDET * 6 + (size_t)b * (MAXDET * NCLS);
    for (int t = wid; t < MAXDET; t += 16) {
        float* dst = lbase + (size_t)t * NCLS;
        if (t < kc) {
            const float* src = logb + (size_t)kidx[t] * NCLS;
            for (int c = lane; c < NCLS; c += 64) dst[c] = src[c];
        } else {
            for (int c = lane; c < NCLS; c += 64) dst[c] = 0.0f;
        }
    }
}

extern "C" void kernel_launch(void* const* d_in, const int* in_sizes, int n_in,
                              void* d_out, int out_size, void* d_ws, size_t ws_size,
                              hipStream_t stream) {
    const float* pred   = (const float*)d_in[0];
    const float* logits = (const float*)d_in[1];
    float* out = (float*)d_out;

    // ws layout (all offsets 8B-aligned)
    const size_t off_hist = 0;                          // 8*1024*4 = 32768
    const size_t off_cnt  = 32768;                      // 8*4 = 32
    const size_t off_key  = 32800;                      // 8*512*8 = 32768
    const size_t off_sel  = 65568;                      // 8 arrays * 16384 = 131072
    const size_t off_ord  = off_sel + 8 * 16384;        // 196640; 8 arrays * 16384
    const size_t off_mask = off_ord + 8 * 16384;        // 327712; 8*4096*8 = 262144
    const size_t off_sws  = off_mask + 262144;          // 589856; 8*25200*4 = 806400
    const size_t need     = off_sws + (size_t)NB * NN * 4;   // 1,396,256

    if (d_ws == nullptr || ws_size < need) {
        fallback_kernel<<<NB, 1024, 0, stream>>>(pred, logits, out);
        return;
    }

    char* ws = (char*)d_ws;
    int* hist = (int*)(ws + off_hist);
    int* cnt_ws = (int*)(ws + off_cnt);
    ull* sel_key = (ull*)(ws + off_key);
    float* sel_x1 = (float*)(ws + off_sel);
    float* sel_y1 = sel_x1 + NB * SELN;
    float* sel_x2 = sel_y1 + NB * SELN;
    float* sel_y2 = sel_x2 + NB * SELN;
    float* sel_area = sel_y2 + NB * SELN;
    float* sel_score = sel_area + NB * SELN;
    float* sel_cls = sel_score + NB * SELN;
    int*   sel_idx = (int*)(sel_cls + NB * SELN);
    float* ord_x1 = (float*)(ws + off_ord);
    float* ord_y1 = ord_x1 + NB * SELN;
    float* ord_x2 = ord_y1 + NB * SELN;
    float* ord_y2 = ord_x2 + NB * SELN;
    float* ord_area = ord_y2 + NB * SELN;
    float* ord_score = ord_area + NB * SELN;
    float* ord_cls = ord_score + NB * SELN;
    int*   ord_idx = (int*)(ord_cls + NB * SELN);
    ull* mask_ws = (ull*)(ws + off_mask);
    float* score_ws = (float*)(ws + off_sws);

    // zero hist + counters with our own kernel (runtime fill had ~40us fixed cost)
    const int nzero = (int)(off_key / 4);   // 8200 ints
    zero_kernel<<<(nzero + 255) / 256, 256, 0, stream>>>((int*)ws, nzero);

    prep_kernel<<<(NB * NN) / PREP_ROWS, 256, 0, stream>>>(pred, score_ws, hist);
    select_kernel<<<NB * BPI, 256, 0, stream>>>(pred, score_ws, hist, cnt_ws,
                                                sel_key, sel_x1, sel_y1, sel_x2, sel_y2,
                                                sel_area, sel_score, sel_cls, sel_idx);
    rank_kernel<<<NB, 512, 0, stream>>>(cnt_ws, sel_key, sel_x1, sel_y1, sel_x2, sel_y2,
                                        sel_area, sel_score, sel_cls, sel_idx,
                                        ord_x1, ord_y1, ord_x2, ord_y2,
                                        ord_area, ord_score, ord_cls, ord_idx);
    mask_kernel<<<NB * 16, 256, 0, stream>>>(cnt_ws, ord_x1, ord_y1, ord_x2, ord_y2,
                                             ord_area, mask_ws);
    resolve_kernel<<<NB, 1024, 0, stream>>>(pred, logits, score_ws, hist, cnt_ws, mask_ws,
                                            ord_x1, ord_y1, ord_x2, ord_y2,
                                            ord_area, ord_score, ord_cls, ord_idx, out);
}